// Round 6
// baseline (1516.654 us; speedup 1.0000x reference)
//
#include <hip/hip_runtime.h>
#include <math.h>
#include <stddef.h>

#define L9   9
#define NB   2
#define CF   1024
#define HW   400     // 20*20
#define CH   256
#define TEMPF 20.0f
#define EPSF  1e-12f

typedef _Float16 half8 __attribute__((ext_vector_type(8)));
typedef float f32x4 __attribute__((ext_vector_type(4)));
typedef unsigned short ushort_t;

// ---------------------------------------------------------------------------
// Kernel 1: partial sums of squares over C for l2norm of fq_feats / fs_feats.
// ---------------------------------------------------------------------------
__global__ __launch_bounds__(256) void norm_partial(const float* __restrict__ fq,
                                                    const float* __restrict__ fs,
                                                    float* __restrict__ partial) {
    int t = blockIdx.y;
    int lb = blockIdx.x >> 3;
    int chunk = blockIdx.x & 7;
    const float* src = (t == 0 ? fq : fs) + (size_t)lb * CF * HW;
    int c0 = chunk * 128;
    int tid = threadIdx.x;
    float acc0 = 0.f, acc1 = 0.f;
    for (int c = c0; c < c0 + 128; ++c) {
        const float* row = src + (size_t)c * HW;
        float v0 = row[tid];
        acc0 = fmaf(v0, v0, acc0);
        if (tid < HW - 256) { float v1 = row[tid + 256]; acc1 = fmaf(v1, v1, acc1); }
    }
    float* dst = partial + ((size_t)(t * 18 + lb) * 8 + chunk) * HW;
    dst[tid] = acc0;
    if (tid < HW - 256) dst[tid + 256] = acc1;
}

// ---------------------------------------------------------------------------
// Kernel 2: finalize inverse norms.
// ---------------------------------------------------------------------------
__global__ __launch_bounds__(256) void norm_finalize(const float* __restrict__ partial,
                                                     float* __restrict__ invn) {
    int idx = blockIdx.x * 256 + threadIdx.x;
    if (idx >= 2 * 18 * HW) return;
    int t_lb = idx / HW;
    int ij = idx - t_lb * HW;
    const float* p = partial + (size_t)t_lb * 8 * HW + ij;
    float ss = 0.f;
    #pragma unroll
    for (int c = 0; c < 8; ++c) ss += p[c * HW];
    invn[idx] = 1.0f / fmaxf(sqrtf(ss), EPSF);
}

// ---------------------------------------------------------------------------
// Kernel 3a: transpose+convert: fq[lb][c][ij] -> At[li][ij][c] fp16 (ditto fs->Bt)
// ---------------------------------------------------------------------------
__global__ __launch_bounds__(256) void transpose_f16(const float* __restrict__ fq,
                                                     const float* __restrict__ fs,
                                                     ushort_t* __restrict__ At,
                                                     ushort_t* __restrict__ Bt,
                                                     int lb_base) {
    __shared__ float tile[64][65];
    int z = blockIdx.z;
    int tsel = z / 9, li = z - tsel * 9;
    int lb = lb_base + li;
    const float* src = (tsel ? fs : fq) + (size_t)lb * CF * HW;
    ushort_t* dst = (tsel ? Bt : At) + (size_t)li * HW * CF;
    int c0 = blockIdx.x * 64, ij0 = blockIdx.y * 64;
    int tid = threadIdx.x;
    int cl = tid >> 6;
    int col = tid & 63;
    #pragma unroll
    for (int rr = 0; rr < 16; ++rr) {
        int c_local = rr * 4 + cl;
        int ij = ij0 + col;
        tile[c_local][col] = (ij < HW) ? src[(size_t)(c0 + c_local) * HW + ij] : 0.f;
    }
    __syncthreads();
    int cp = (tid & 31) * 2;
    int rowsel = tid >> 5;
    #pragma unroll
    for (int rr = 0; rr < 8; ++rr) {
        int ij_local = rr * 8 + rowsel;
        int ij = ij0 + ij_local;
        if (ij < HW) {
            union { _Float16 h; ushort_t u; } h0, h1;
            h0.h = (_Float16)tile[cp][ij_local];
            h1.h = (_Float16)tile[cp + 1][ij_local];
            ushort2 o; o.x = h0.u; o.y = h1.u;
            *(ushort2*)(dst + (size_t)ij * CF + c0 + cp) = o;
        }
    }
}

// ---------------------------------------------------------------------------
// Kernel 3b: MFMA fp16 correlation GEMM (verified R3).
// ---------------------------------------------------------------------------
__global__ __launch_bounds__(256) void corr_gemm_mfma(const ushort_t* __restrict__ At,
                                                      const ushort_t* __restrict__ Bt,
                                                      const float* __restrict__ invn,
                                                      float* __restrict__ corr,
                                                      int lb_base) {
    __shared__ ushort_t As[64][72];
    __shared__ ushort_t Bs[64][72];
    int li = blockIdx.z, lb = lb_base + li;
    int l = lb >> 1, b = lb & 1;
    int i0 = blockIdx.y * 64, j0 = blockIdx.x * 64;
    int tid = threadIdx.x, lane = tid & 63, w = tid >> 6;
    int mw = (w >> 1) * 32, nw = (w & 1) * 32;
    f32x4 acc[2][2] = {};
    const ushort_t* Abase = At + (size_t)li * HW * CF;
    const ushort_t* Bbase = Bt + (size_t)li * HW * CF;

    for (int kt = 0; kt < 16; ++kt) {
        int c0 = kt * 64;
        __syncthreads();
        #pragma unroll
        for (int p = 0; p < 2; ++p) {
            int idx = tid + p * 256;
            int row = idx >> 3, c8 = idx & 7;
            uint4 va = make_uint4(0, 0, 0, 0), vb = make_uint4(0, 0, 0, 0);
            if (i0 + row < HW) va = *(const uint4*)(Abase + (size_t)(i0 + row) * CF + c0 + c8 * 8);
            if (j0 + row < HW) vb = *(const uint4*)(Bbase + (size_t)(j0 + row) * CF + c0 + c8 * 8);
            *(uint4*)&As[row][c8 * 8] = va;
            *(uint4*)&Bs[row][c8 * 8] = vb;
        }
        __syncthreads();
        #pragma unroll
        for (int ks = 0; ks < 2; ++ks) {
            int k0 = ks * 32 + (lane >> 4) * 8;
            half8 a0 = *(const half8*)&As[mw + (lane & 15)][k0];
            half8 a1 = *(const half8*)&As[mw + 16 + (lane & 15)][k0];
            half8 b0 = *(const half8*)&Bs[nw + (lane & 15)][k0];
            half8 b1 = *(const half8*)&Bs[nw + 16 + (lane & 15)][k0];
            acc[0][0] = __builtin_amdgcn_mfma_f32_16x16x32_f16(a0, b0, acc[0][0], 0, 0, 0);
            acc[0][1] = __builtin_amdgcn_mfma_f32_16x16x32_f16(a0, b1, acc[0][1], 0, 0, 0);
            acc[1][0] = __builtin_amdgcn_mfma_f32_16x16x32_f16(a1, b0, acc[1][0], 0, 0, 0);
            acc[1][1] = __builtin_amdgcn_mfma_f32_16x16x32_f16(a1, b1, acc[1][1], 0, 0, 0);
        }
    }
    int obase = (b * 9 + l) * HW;
    #pragma unroll
    for (int mi = 0; mi < 2; ++mi) {
        #pragma unroll
        for (int ni = 0; ni < 2; ++ni) {
            #pragma unroll
            for (int r = 0; r < 4; ++r) {
                int ij = i0 + mw + mi * 16 + (lane >> 4) * 4 + r;
                int km = j0 + nw + ni * 16 + (lane & 15);
                if (ij < HW && km < HW)
                    corr[(size_t)(obase + ij) * HW + km] =
                        acc[mi][ni][r] * invn[lb * HW + ij] * invn[7200 + lb * HW + km];
            }
        }
    }
}

// ---------------------------------------------------------------------------
// Kernel W: weight prep — build B-fragment tables in fp16.
// wb[chunk][dd][n16][64]: B[k=(ci_local,pl,hi/lo)][n=co], w duplicated in
// hi/lo slots (activation hi+lo split in K). SWAP folds the transposed path.
// ---------------------------------------------------------------------------
template <int CIN, int COUT, bool SWAP>
__global__ __launch_bounds__(256) void wprep(const float* __restrict__ wt,
                                             ushort_t* __restrict__ wb) {
    const int NCH = (CIN + 2) / 3;
    int idx = blockIdx.x * 256 + threadIdx.x;
    int total = NCH * 9 * 16 * 64;
    if (idx >= total) return;
    int c = idx & 63, n = (idx >> 6) & 15, dd = (idx >> 10) % 9, ch = idx / 9216;
    int nc = CIN - ch * 3; if (nc > 3) nc = 3;
    int pslot = c >> 1;
    float v = 0.f;
    if (n < COUT && pslot < nc * 9) {
        int cil = pslot / 9, pl = pslot - cil * 9, ci = ch * 3 + cil;
        int di = pl / 3, dj = pl % 3, dk = dd / 3, dm = dd % 3;
        int widx = SWAP ? ((((n * CIN + ci) * 3 + dk) * 3 + dm) * 3 + di) * 3 + dj
                        : ((((n * CIN + ci) * 3 + di) * 3 + dj) * 3 + dk) * 3 + dm;
        v = wt[widx];
    }
    union { _Float16 h; ushort_t u; } cv; cv.h = (_Float16)v;
    wb[idx] = cv.u;
}

// ---------------------------------------------------------------------------
// Kernel 4 (v4): 4D conv + ReLU via MFMA implicit GEMM.
// Block = (b, ij). For each dd=(dk,dm): C[km, co] += A_dd[km, K] B_dd[K, co],
// A_dd[km, (ci,pl,s)] = halo-plane value at (k+dk, m+dm), s = fp16 hi/lo split.
// LDS Ah[row = kk*22+mm][64 halfs], rows 128 B, XOR-granule swizzle
// (granule' = granule ^ (row&7)) -> ~2-way on both staged writes & frag reads.
// K chunked 3 ci at a time (K=54 real -> 2 MFMA k-steps of 32).
// R5 fix: zero ALL of Ah (22*22*32 uints, was 22*22*16 — half the tile stayed
// uninitialized garbage -> NaN via halo reads).
// ---------------------------------------------------------------------------
template <int CIN, int COUT, bool ACCUM>
__global__ __launch_bounds__(256) void conv4d_mfma(const float* __restrict__ in,
                                                   const ushort_t* __restrict__ wb,
                                                   float* __restrict__ out) {
    const int NCH = (CIN + 2) / 3;
    __shared__ ushort_t Ah[22 * 22 * 64];   // 61,952 B
    const int b = blockIdx.y, ij = blockIdx.x;
    const int i = ij / 20, j = ij - (ij / 20) * 20;
    const int tid = threadIdx.x, lane = tid & 63, wv = tid >> 6;

    // full zero (halo + K-pad stay zero)
    {
        uint* A4 = (uint*)Ah;
        for (int p = tid; p < 22 * 22 * 32; p += 256) A4[p] = 0;
    }

    // Mtile ownership + per-lane A-row bases (row = k*22 + m, halo offset via dd)
    int rowb[7];
    int nS = 0;
    for (int t = wv; t < 25; t += 4, ++nS) {
        int km = t * 16 + (lane & 15);
        int kk = km / 20, mm = km - kk * 20;
        rowb[nS] = kk * 22 + mm;
    }
    f32x4 acc[7] = {};

    // staging mapping: p = plane slot (ci_local*9+pl), kslot picks float4 column
    const int p = tid >> 3, kslot = tid & 7;
    const int cil = p / 9, pl = p - cil * 9;
    const int di = pl / 3, dj = pl - di * 3;
    const int ii = i + di - 1, jj = j + dj - 1;
    const bool inplane = (unsigned)ii < 20u && (unsigned)jj < 20u;
    const int q = lane >> 4;
    const ushort_t* wbn = wb + (lane & 15) * 64 + q * 8;

    for (int ch = 0; ch < NCH; ++ch) {
        int nc = CIN - ch * 3; if (nc > 3) nc = 3;
        __syncthreads();   // prior chunk's MFMA reads done
        // tail-zero stale K slots when chunk shrinks (CIN=10 last chunk)
        if (ch > 0 && nc < 3) {
            int nw = 27 - nc * 9;
            for (int z = tid; z < 484 * nw; z += 256) {
                int row = z / nw, w = nc * 9 + z - (z / nw) * nw;
                int phys = (((w >> 2) ^ (row & 7)) << 2) | (w & 3);
                ((uint*)Ah)[row * 32 + phys] = 0;
            }
        }
        // stage: fp32 -> (hi,lo) f16 pair packed in one b32 at word p of each row
        if (p < nc * 9) {
            const float* src = in + ((size_t)(b * CIN + ch * 3 + cil) * HW + ii * 20 + jj) * HW;
            #pragma unroll 1
            for (int e = kslot; e < 100; e += 8) {
                float4 v = inplane ? *(const float4*)(src + e * 4)
                                   : make_float4(0.f, 0.f, 0.f, 0.f);
                int km0 = e * 4;
                int kk = km0 / 20, m0 = km0 - kk * 20;
                int rbase = (kk + 1) * 22 + (m0 + 1);
                float vv[4] = {v.x, v.y, v.z, v.w};
                #pragma unroll
                for (int t4 = 0; t4 < 4; ++t4) {
                    int row = rbase + t4;
                    _Float16 hi = (_Float16)vv[t4];
                    _Float16 lo = (_Float16)(vv[t4] - (float)hi);
                    union { struct { _Float16 a, b2; } s; uint u; } pk;
                    pk.s.a = hi; pk.s.b2 = lo;
                    int phys = (((p >> 2) ^ (row & 7)) << 2) | (p & 3);
                    ((uint*)Ah)[row * 32 + phys] = pk.u;
                }
            }
        }
        __syncthreads();
        // MFMA phase
        int ksteps = (nc * 18 > 32) ? 2 : 1;
        const ushort_t* wbc = wbn + (size_t)ch * 9216;
        for (int dd = 0; dd < 9; ++dd) {
            int ddofs = (dd / 3) * 22 + (dd % 3);
            const ushort_t* wbd = wbc + dd * 1024;
            for (int ks = 0; ks < ksteps; ++ks) {
                half8 bf = *(const half8*)(wbd + ks * 32);
                int glog = ks * 4 + q;
                int s = 0;
                for (int t = wv; t < 25; t += 4, ++s) {
                    int row = rowb[s] + ddofs;
                    int phys = glog ^ (row & 7);
                    half8 af = *(const half8*)(Ah + row * 64 + phys * 8);
                    acc[s] = __builtin_amdgcn_mfma_f32_16x16x32_f16(af, bf, acc[s], 0, 0, 0);
                }
            }
        }
    }

    // epilogue: C/D col=lane&15 -> co, row=(lane>>4)*4+r -> km within tile
    const int co = lane & 15;
    if (co < COUT) {
        int s = 0;
        for (int t = wv; t < 25; t += 4, ++s) {
            int km0 = t * 16 + q * 4;
            float* op = out + (((size_t)(b * COUT + co) * HW + ij) * HW + km0);
            #pragma unroll
            for (int r = 0; r < 4; ++r) {
                float v = fmaxf(acc[s][r], 0.f);
                if (ACCUM) op[r] += v; else op[r] = v;
            }
        }
    }
}

// ---------------------------------------------------------------------------
// Kernel 5: softmax over s + att_fq = attn . V
// ---------------------------------------------------------------------------
__global__ __launch_bounds__(256) void softmax_av(const float* __restrict__ c4,
                                                  const float* __restrict__ f_s,
                                                  float* __restrict__ att_out) {
    __shared__ float p[HW];
    __shared__ float red[256];
    int b = blockIdx.y, q = blockIdx.x;
    int tid = threadIdx.x;
    const float* row = c4 + ((size_t)b * HW + q) * HW;
    float v0 = row[tid] * TEMPF;
    float v1 = (tid < HW - 256) ? row[tid + 256] * TEMPF : -1e30f;
    red[tid] = fmaxf(v0, v1);
    __syncthreads();
    for (int s = 128; s > 0; s >>= 1) {
        if (tid < s) red[tid] = fmaxf(red[tid], red[tid + s]);
        __syncthreads();
    }
    float mx = red[0];
    __syncthreads();
    float e0 = expf(v0 - mx);
    float e1 = (tid < HW - 256) ? expf(v1 - mx) : 0.f;
    p[tid] = e0;
    if (tid < HW - 256) p[tid + 256] = e1;
    red[tid] = e0 + e1;
    __syncthreads();
    for (int s = 128; s > 0; s >>= 1) {
        if (tid < s) red[tid] += red[tid + s];
        __syncthreads();
    }
    float inv = 1.0f / red[0];
    const float* vrow = f_s + (size_t)(b * CH + tid) * HW;
    float acc = 0.f;
    for (int s = 0; s < HW; ++s) acc = fmaf(p[s], vrow[s], acc);
    att_out[(size_t)(b * CH + tid) * HW + q] = acc * inv;
}

// ---------------------------------------------------------------------------
// Kernel 6: fq = l2norm(f_q, ch) + 0.5 * l2norm(att_fq, ch)
// ---------------------------------------------------------------------------
__global__ __launch_bounds__(256) void final_fq(const float* __restrict__ f_q,
                                                const float* __restrict__ att,
                                                float* __restrict__ out_fq) {
    __shared__ float red[256];
    int b = blockIdx.y, q = blockIdx.x;
    int tid = threadIdx.x;
    size_t idx = (size_t)(b * CH + tid) * HW + q;
    float f = f_q[idx];
    float a = att[idx];
    red[tid] = f * f;
    __syncthreads();
    for (int s = 128; s > 0; s >>= 1) {
        if (tid < s) red[tid] += red[tid + s];
        __syncthreads();
    }
    float invf = 1.0f / fmaxf(sqrtf(red[0]), EPSF);
    __syncthreads();
    red[tid] = a * a;
    __syncthreads();
    for (int s = 128; s > 0; s >>= 1) {
        if (tid < s) red[tid] += red[tid + s];
        __syncthreads();
    }
    float inva = 1.0f / fmaxf(sqrtf(red[0]), EPSF);
    out_fq[idx] = f * invf + 0.5f * a * inva;
}

// ---------------------------------------------------------------------------
extern "C" void kernel_launch(void* const* d_in, const int* in_sizes, int n_in,
                              void* d_out, int out_size, void* d_ws, size_t ws_size,
                              hipStream_t stream) {
    const float* fq_feats = (const float*)d_in[0];
    const float* fs_feats = (const float*)d_in[1];
    const float* f_q      = (const float*)d_in[2];
    const float* f_s      = (const float*)d_in[3];
    const float* w1       = (const float*)d_in[4];
    const float* w2       = (const float*)d_in[5];
    const float* w3       = (const float*)d_in[6];
    float* out = (float*)d_out;              // fq at 0, att_fq at 204800

    float* ws      = (float*)d_ws;
    float* partial = ws;                     // 115,200 fl (reused as wbuf later)
    float* invn    = partial + 115200;       // 14,400
    float* corr    = invn + 14400;           // 2,880,000
    float* buf1    = corr + 2880000;         // 3,200,000
    float* buf2    = buf1 + 3200000;         // 3,200,000
    float* c4      = buf2 + 3200000;         // 320,000
    float* att     = out + 204800;

    ushort_t* At = (ushort_t*)buf1;
    ushort_t* Bt = (ushort_t*)buf2;

    // wbuf tables overlay `partial` (dead after norm_finalize):
    ushort_t* wb0   = (ushort_t*)partial;
    ushort_t* wbL1A = wb0;
    ushort_t* wbL1B = wb0 + 27648;
    ushort_t* wbL2A = wb0 + 55296;
    ushort_t* wbL2B = wb0 + 92160;
    ushort_t* wbL3A = wb0 + 129024;
    ushort_t* wbL3B = wb0 + 165888;          // ends 202,752 < 230,400 halfs ok

    norm_partial<<<dim3(18 * 8, 2), 256, 0, stream>>>(fq_feats, fs_feats, partial);
    norm_finalize<<<(2 * 18 * HW + 255) / 256, 256, 0, stream>>>(partial, invn);

    // weight prep (after norm_finalize frees `partial`)
    wprep<9, 10, false><<<108, 256, 0, stream>>>(w1, wbL1A);
    wprep<9, 10, true ><<<108, 256, 0, stream>>>(w1, wbL1B);
    wprep<10, 10, false><<<144, 256, 0, stream>>>(w2, wbL2A);
    wprep<10, 10, true ><<<144, 256, 0, stream>>>(w2, wbL2B);
    wprep<10, 1, false><<<144, 256, 0, stream>>>(w3, wbL3A);
    wprep<10, 1, true ><<<144, 256, 0, stream>>>(w3, wbL3B);

    // correlation GEMM in two l-batches of 9 (buffers reused)
    for (int half = 0; half < 2; ++half) {
        int base = half * 9;
        transpose_f16<<<dim3(16, 7, 18), 256, 0, stream>>>(fq_feats, fs_feats, At, Bt, base);
        corr_gemm_mfma<<<dim3(7, 7, 9), 256, 0, stream>>>(At, Bt, invn, corr, base);
    }

    // path A
    conv4d_mfma<9, 10, false><<<dim3(400, NB), 256, 0, stream>>>(corr, wbL1A, buf1);
    conv4d_mfma<10, 10, false><<<dim3(400, NB), 256, 0, stream>>>(buf1, wbL2A, buf2);
    conv4d_mfma<10, 1, false><<<dim3(400, NB), 256, 0, stream>>>(buf2, wbL3A, c4);
    // path B (tap-swapped weights), accumulated into c4
    conv4d_mfma<9, 10, false><<<dim3(400, NB), 256, 0, stream>>>(corr, wbL1B, buf1);
    conv4d_mfma<10, 10, false><<<dim3(400, NB), 256, 0, stream>>>(buf1, wbL2B, buf2);
    conv4d_mfma<10, 1, true ><<<dim3(400, NB), 256, 0, stream>>>(buf2, wbL3B, c4);

    softmax_av<<<dim3(400, NB), 256, 0, stream>>>(c4, f_s, att);
    final_fq<<<dim3(400, NB), 256, 0, stream>>>(f_q, att, out);

    (void)in_sizes; (void)n_in; (void)out_size; (void)ws_size;
}

// Round 7
// 561.978 us; speedup vs baseline: 2.6988x; 2.6988x over previous
//
#include <hip/hip_runtime.h>
#include <math.h>
#include <stddef.h>

#define L9   9
#define NB   2
#define CF   1024
#define HW   400     // 20*20
#define CH   256
#define TEMPF 20.0f
#define EPSF  1e-12f

typedef _Float16 half8 __attribute__((ext_vector_type(8)));
typedef float f32x4 __attribute__((ext_vector_type(4)));
typedef unsigned short ushort_t;

// ---------------------------------------------------------------------------
// Kernel 1: partial sums of squares over C for l2norm of fq_feats / fs_feats.
// ---------------------------------------------------------------------------
__global__ __launch_bounds__(256) void norm_partial(const float* __restrict__ fq,
                                                    const float* __restrict__ fs,
                                                    float* __restrict__ partial) {
    int t = blockIdx.y;
    int lb = blockIdx.x >> 3;
    int chunk = blockIdx.x & 7;
    const float* src = (t == 0 ? fq : fs) + (size_t)lb * CF * HW;
    int c0 = chunk * 128;
    int tid = threadIdx.x;
    float acc0 = 0.f, acc1 = 0.f;
    for (int c = c0; c < c0 + 128; ++c) {
        const float* row = src + (size_t)c * HW;
        float v0 = row[tid];
        acc0 = fmaf(v0, v0, acc0);
        if (tid < HW - 256) { float v1 = row[tid + 256]; acc1 = fmaf(v1, v1, acc1); }
    }
    float* dst = partial + ((size_t)(t * 18 + lb) * 8 + chunk) * HW;
    dst[tid] = acc0;
    if (tid < HW - 256) dst[tid + 256] = acc1;
}

// ---------------------------------------------------------------------------
// Kernel 2: finalize inverse norms.
// ---------------------------------------------------------------------------
__global__ __launch_bounds__(256) void norm_finalize(const float* __restrict__ partial,
                                                     float* __restrict__ invn) {
    int idx = blockIdx.x * 256 + threadIdx.x;
    if (idx >= 2 * 18 * HW) return;
    int t_lb = idx / HW;
    int ij = idx - t_lb * HW;
    const float* p = partial + (size_t)t_lb * 8 * HW + ij;
    float ss = 0.f;
    #pragma unroll
    for (int c = 0; c < 8; ++c) ss += p[c * HW];
    invn[idx] = 1.0f / fmaxf(sqrtf(ss), EPSF);
}

// ---------------------------------------------------------------------------
// Kernel 3a: transpose+convert: fq[lb][c][ij] -> At[li][ij][c] fp16 (ditto fs->Bt)
// ---------------------------------------------------------------------------
__global__ __launch_bounds__(256) void transpose_f16(const float* __restrict__ fq,
                                                     const float* __restrict__ fs,
                                                     ushort_t* __restrict__ At,
                                                     ushort_t* __restrict__ Bt,
                                                     int lb_base) {
    __shared__ float tile[64][65];
    int z = blockIdx.z;
    int tsel = z / 9, li = z - tsel * 9;
    int lb = lb_base + li;
    const float* src = (tsel ? fs : fq) + (size_t)lb * CF * HW;
    ushort_t* dst = (tsel ? Bt : At) + (size_t)li * HW * CF;
    int c0 = blockIdx.x * 64, ij0 = blockIdx.y * 64;
    int tid = threadIdx.x;
    int cl = tid >> 6;
    int col = tid & 63;
    #pragma unroll
    for (int rr = 0; rr < 16; ++rr) {
        int c_local = rr * 4 + cl;
        int ij = ij0 + col;
        tile[c_local][col] = (ij < HW) ? src[(size_t)(c0 + c_local) * HW + ij] : 0.f;
    }
    __syncthreads();
    int cp = (tid & 31) * 2;
    int rowsel = tid >> 5;
    #pragma unroll
    for (int rr = 0; rr < 8; ++rr) {
        int ij_local = rr * 8 + rowsel;
        int ij = ij0 + ij_local;
        if (ij < HW) {
            union { _Float16 h; ushort_t u; } h0, h1;
            h0.h = (_Float16)tile[cp][ij_local];
            h1.h = (_Float16)tile[cp + 1][ij_local];
            ushort2 o; o.x = h0.u; o.y = h1.u;
            *(ushort2*)(dst + (size_t)ij * CF + c0 + cp) = o;
        }
    }
}

// ---------------------------------------------------------------------------
// Kernel 3b: MFMA fp16 correlation GEMM (verified R3).
// ---------------------------------------------------------------------------
__global__ __launch_bounds__(256) void corr_gemm_mfma(const ushort_t* __restrict__ At,
                                                      const ushort_t* __restrict__ Bt,
                                                      const float* __restrict__ invn,
                                                      float* __restrict__ corr,
                                                      int lb_base) {
    __shared__ ushort_t As[64][72];
    __shared__ ushort_t Bs[64][72];
    int li = blockIdx.z, lb = lb_base + li;
    int l = lb >> 1, b = lb & 1;
    int i0 = blockIdx.y * 64, j0 = blockIdx.x * 64;
    int tid = threadIdx.x, lane = tid & 63, w = tid >> 6;
    int mw = (w >> 1) * 32, nw = (w & 1) * 32;
    f32x4 acc[2][2] = {};
    const ushort_t* Abase = At + (size_t)li * HW * CF;
    const ushort_t* Bbase = Bt + (size_t)li * HW * CF;

    for (int kt = 0; kt < 16; ++kt) {
        int c0 = kt * 64;
        __syncthreads();
        #pragma unroll
        for (int p = 0; p < 2; ++p) {
            int idx = tid + p * 256;
            int row = idx >> 3, c8 = idx & 7;
            uint4 va = make_uint4(0, 0, 0, 0), vb = make_uint4(0, 0, 0, 0);
            if (i0 + row < HW) va = *(const uint4*)(Abase + (size_t)(i0 + row) * CF + c0 + c8 * 8);
            if (j0 + row < HW) vb = *(const uint4*)(Bbase + (size_t)(j0 + row) * CF + c0 + c8 * 8);
            *(uint4*)&As[row][c8 * 8] = va;
            *(uint4*)&Bs[row][c8 * 8] = vb;
        }
        __syncthreads();
        #pragma unroll
        for (int ks = 0; ks < 2; ++ks) {
            int k0 = ks * 32 + (lane >> 4) * 8;
            half8 a0 = *(const half8*)&As[mw + (lane & 15)][k0];
            half8 a1 = *(const half8*)&As[mw + 16 + (lane & 15)][k0];
            half8 b0 = *(const half8*)&Bs[nw + (lane & 15)][k0];
            half8 b1 = *(const half8*)&Bs[nw + 16 + (lane & 15)][k0];
            acc[0][0] = __builtin_amdgcn_mfma_f32_16x16x32_f16(a0, b0, acc[0][0], 0, 0, 0);
            acc[0][1] = __builtin_amdgcn_mfma_f32_16x16x32_f16(a0, b1, acc[0][1], 0, 0, 0);
            acc[1][0] = __builtin_amdgcn_mfma_f32_16x16x32_f16(a1, b0, acc[1][0], 0, 0, 0);
            acc[1][1] = __builtin_amdgcn_mfma_f32_16x16x32_f16(a1, b1, acc[1][1], 0, 0, 0);
        }
    }
    int obase = (b * 9 + l) * HW;
    #pragma unroll
    for (int mi = 0; mi < 2; ++mi) {
        #pragma unroll
        for (int ni = 0; ni < 2; ++ni) {
            #pragma unroll
            for (int r = 0; r < 4; ++r) {
                int ij = i0 + mw + mi * 16 + (lane >> 4) * 4 + r;
                int km = j0 + nw + ni * 16 + (lane & 15);
                if (ij < HW && km < HW)
                    corr[(size_t)(obase + ij) * HW + km] =
                        acc[mi][ni][r] * invn[lb * HW + ij] * invn[7200 + lb * HW + km];
            }
        }
    }
}

// ---------------------------------------------------------------------------
// Kernel W (v5): weight prep — B-fragment tables, fp16, NO hi/lo duplication.
// wb[ch][dd][n(16)][k(32)]: k = ci_local*9 + pl(di,dj), zero-padded to 32.
// 4608 halfs per chunk. SWAP folds the transposed path.
// ---------------------------------------------------------------------------
template <int CIN, int COUT, bool SWAP>
__global__ __launch_bounds__(256) void wprep(const float* __restrict__ wt,
                                             ushort_t* __restrict__ wb) {
    const int NCH = (CIN + 2) / 3;
    int idx = blockIdx.x * 256 + threadIdx.x;
    int total = NCH * 4608;
    if (idx >= total) return;
    int k = idx & 31, n = (idx >> 5) & 15, dd = (idx >> 9) % 9, ch = idx / 4608;
    int nc = CIN - ch * 3; if (nc > 3) nc = 3;
    float v = 0.f;
    if (n < COUT && k < nc * 9) {
        int cil = k / 9, pl = k - cil * 9, ci = ch * 3 + cil;
        int di = pl / 3, dj = pl % 3, dk = dd / 3, dm = dd % 3;
        int widx = SWAP ? ((((n * CIN + ci) * 3 + dk) * 3 + dm) * 3 + di) * 3 + dj
                        : ((((n * CIN + ci) * 3 + di) * 3 + dj) * 3 + dk) * 3 + dm;
        v = wt[widx];
    }
    union { _Float16 h; ushort_t u; } cv; cv.h = (_Float16)v;
    wb[idx] = cv.u;
}

// ---------------------------------------------------------------------------
// Kernel 4 (v5): 4D conv + ReLU via MFMA implicit GEMM, plain f16.
// Block = (b, ij). Per dd=(dk,dm): C[km, co] += A_dd[km, K] B_dd[K, co],
// K = (ci_local, pl=(di,dj)) chunked 3 ci at a time -> K=27 in ONE 32-k-step.
// LDS Ah[484 halo rows][40 halfs] (38.7 KB): row stride 80 B gives a
// period-8 bank-start pattern -> <=2-way conflicts, NO swizzle; fragment
// reads = base VGPR + compile-time immediate offset (zero VALU per read).
// Staging: thread owns row km; 4 k-slots packed per ds_write_b64.
// Halo rows / k-pad zeroed once; stale tail-chunk columns hit zero weights.
// ---------------------------------------------------------------------------
template <int CIN, int COUT, bool ACCUM>
__global__ __launch_bounds__(256) void conv4d_v5(const float* __restrict__ in,
                                                 const ushort_t* __restrict__ wb,
                                                 float* __restrict__ out) {
    constexpr int NCH = (CIN + 2) / 3;
    __shared__ __align__(16) ushort_t Ah[484 * 40];   // 38,720 B
    const int b = blockIdx.y, ij = blockIdx.x;
    const int i = ij / 20, j = ij - (ij / 20) * 20;
    const int tid = threadIdx.x, wv = tid >> 6, lane = tid & 63;
    const int m16 = lane & 15, q = lane >> 4;

    for (int p = tid; p < 484 * 20; p += 256) ((uint*)Ah)[p] = 0;

    // per-lane M-tile fragment bases (half-index into Ah)
    int baseh[7];
    #pragma unroll
    for (int s = 0; s < 7; ++s) {
        int t = wv + 4 * s;
        if (t < 25) {
            int km = t * 16 + m16;
            int kk = km / 20, mm = km - kk * 20;
            baseh[s] = (kk * 22 + mm) * 40 + q * 8;
        } else baseh[s] = 0;
    }
    f32x4 acc[7] = {};

    const float* in_b = in + (size_t)b * CIN * HW * HW;
    const ushort_t* wfr = wb + m16 * 32 + q * 8;

    const int km1 = tid;
    const int km2 = tid + 256;
    const bool r2ok = tid < 144;
    const int r1 = (km1 / 20 + 1) * 22 + (km1 % 20) + 1;
    const int r2 = (km2 / 20 + 1) * 22 + (km2 % 20) + 1;

    __syncthreads();   // zeroing complete

    #pragma unroll
    for (int ch = 0; ch < NCH; ++ch) {
        const int nc = (CIN - ch * 3 > 3) ? 3 : (CIN - ch * 3);
        if (ch > 0) __syncthreads();   // prior chunk's fragment reads done
        // ---- stage chunk: rows own km, pack 4 k-slots per b64 write ----
        #pragma unroll
        for (int g4 = 0; g4 < 7; ++g4) {
            if (g4 * 4 < nc * 9) {
                ushort_t h1[4], h2[4];
                #pragma unroll
                for (int u = 0; u < 4; ++u) {
                    const int slot = g4 * 4 + u;
                    float v1 = 0.f, v2 = 0.f;
                    if (slot < nc * 9) {
                        const int cil = slot / 9, pl = slot - cil * 9;
                        const int di = pl / 3, dj = pl - di * 3;
                        const int ii = i + di - 1, jj = j + dj - 1;
                        if ((unsigned)ii < 20u && (unsigned)jj < 20u) {
                            const float* src = in_b + ((size_t)(ch * 3 + cil) * HW + ii * 20 + jj) * HW;
                            v1 = src[km1];
                            if (r2ok) v2 = src[km2];
                        }
                    }
                    union { _Float16 h; ushort_t u16; } c1, c2;
                    c1.h = (_Float16)v1; c2.h = (_Float16)v2;
                    h1[u] = c1.u16; h2[u] = c2.u16;
                }
                union { ushort_t us[4]; uint2 u2; } p1, p2;
                p1.us[0] = h1[0]; p1.us[1] = h1[1]; p1.us[2] = h1[2]; p1.us[3] = h1[3];
                p2.us[0] = h2[0]; p2.us[1] = h2[1]; p2.us[2] = h2[2]; p2.us[3] = h2[3];
                *(uint2*)&Ah[r1 * 40 + g4 * 4] = p1.u2;
                if (r2ok) *(uint2*)&Ah[r2 * 40 + g4 * 4] = p2.u2;
            }
        }
        __syncthreads();
        // ---- MFMA phase: 9 dd x (up to 7 M-tiles), one 32-K-step each ----
        const ushort_t* wch = wfr + ch * 4608;
        #pragma unroll
        for (int dd = 0; dd < 9; ++dd) {
            half8 bf = *(const half8*)(wch + dd * 512);
            const int doff = ((dd / 3) * 22 + (dd % 3)) * 40;
            #pragma unroll
            for (int s = 0; s < 7; ++s) {
                if (wv + 4 * s < 25) {
                    half8 af = *(const half8*)(Ah + baseh[s] + doff);
                    acc[s] = __builtin_amdgcn_mfma_f32_16x16x32_f16(af, bf, acc[s], 0, 0, 0);
                }
            }
        }
    }

    // epilogue: C/D col=lane&15 -> co, row=q*4+r -> km within tile
    const int co = m16;
    if (co < COUT) {
        #pragma unroll
        for (int s = 0; s < 7; ++s) {
            int t = wv + 4 * s;
            if (t < 25) {
                int km0 = t * 16 + q * 4;
                float* op = out + (((size_t)(b * COUT + co) * HW + ij) * HW + km0);
                #pragma unroll
                for (int r = 0; r < 4; ++r) {
                    float v = fmaxf(acc[s][r], 0.f);
                    if (ACCUM) op[r] += v; else op[r] = v;
                }
            }
        }
    }
}

// ---------------------------------------------------------------------------
// Kernel 5: softmax over s + att_fq = attn . V
// ---------------------------------------------------------------------------
__global__ __launch_bounds__(256) void softmax_av(const float* __restrict__ c4,
                                                  const float* __restrict__ f_s,
                                                  float* __restrict__ att_out) {
    __shared__ float p[HW];
    __shared__ float red[256];
    int b = blockIdx.y, q = blockIdx.x;
    int tid = threadIdx.x;
    const float* row = c4 + ((size_t)b * HW + q) * HW;
    float v0 = row[tid] * TEMPF;
    float v1 = (tid < HW - 256) ? row[tid + 256] * TEMPF : -1e30f;
    red[tid] = fmaxf(v0, v1);
    __syncthreads();
    for (int s = 128; s > 0; s >>= 1) {
        if (tid < s) red[tid] = fmaxf(red[tid], red[tid + s]);
        __syncthreads();
    }
    float mx = red[0];
    __syncthreads();
    float e0 = expf(v0 - mx);
    float e1 = (tid < HW - 256) ? expf(v1 - mx) : 0.f;
    p[tid] = e0;
    if (tid < HW - 256) p[tid + 256] = e1;
    red[tid] = e0 + e1;
    __syncthreads();
    for (int s = 128; s > 0; s >>= 1) {
        if (tid < s) red[tid] += red[tid + s];
        __syncthreads();
    }
    float inv = 1.0f / red[0];
    const float* vrow = f_s + (size_t)(b * CH + tid) * HW;
    float acc = 0.f;
    for (int s = 0; s < HW; ++s) acc = fmaf(p[s], vrow[s], acc);
    att_out[(size_t)(b * CH + tid) * HW + q] = acc * inv;
}

// ---------------------------------------------------------------------------
// Kernel 6: fq = l2norm(f_q, ch) + 0.5 * l2norm(att_fq, ch)
// ---------------------------------------------------------------------------
__global__ __launch_bounds__(256) void final_fq(const float* __restrict__ f_q,
                                                const float* __restrict__ att,
                                                float* __restrict__ out_fq) {
    __shared__ float red[256];
    int b = blockIdx.y, q = blockIdx.x;
    int tid = threadIdx.x;
    size_t idx = (size_t)(b * CH + tid) * HW + q;
    float f = f_q[idx];
    float a = att[idx];
    red[tid] = f * f;
    __syncthreads();
    for (int s = 128; s > 0; s >>= 1) {
        if (tid < s) red[tid] += red[tid + s];
        __syncthreads();
    }
    float invf = 1.0f / fmaxf(sqrtf(red[0]), EPSF);
    __syncthreads();
    red[tid] = a * a;
    __syncthreads();
    for (int s = 128; s > 0; s >>= 1) {
        if (tid < s) red[tid] += red[tid + s];
        __syncthreads();
    }
    float inva = 1.0f / fmaxf(sqrtf(red[0]), EPSF);
    out_fq[idx] = f * invf + 0.5f * a * inva;
}

// ---------------------------------------------------------------------------
extern "C" void kernel_launch(void* const* d_in, const int* in_sizes, int n_in,
                              void* d_out, int out_size, void* d_ws, size_t ws_size,
                              hipStream_t stream) {
    const float* fq_feats = (const float*)d_in[0];
    const float* fs_feats = (const float*)d_in[1];
    const float* f_q      = (const float*)d_in[2];
    const float* f_s      = (const float*)d_in[3];
    const float* w1       = (const float*)d_in[4];
    const float* w2       = (const float*)d_in[5];
    const float* w3       = (const float*)d_in[6];
    float* out = (float*)d_out;              // fq at 0, att_fq at 204800

    float* ws      = (float*)d_ws;
    float* partial = ws;                     // 115,200 fl (reused as wbuf later)
    float* invn    = partial + 115200;       // 14,400
    float* corr    = invn + 14400;           // 2,880,000
    float* buf1    = corr + 2880000;         // 3,200,000
    float* buf2    = buf1 + 3200000;         // 3,200,000
    float* c4      = buf2 + 3200000;         // 320,000
    float* att     = out + 204800;

    ushort_t* At = (ushort_t*)buf1;
    ushort_t* Bt = (ushort_t*)buf2;

    // wbuf tables overlay `partial` (dead after norm_finalize):
    // halves: L1 = 3*4608 = 13,824; L2/L3 = 4*4608 = 18,432
    ushort_t* wb0   = (ushort_t*)partial;
    ushort_t* wbL1A = wb0;
    ushort_t* wbL1B = wb0 + 13824;
    ushort_t* wbL2A = wb0 + 27648;
    ushort_t* wbL2B = wb0 + 46080;
    ushort_t* wbL3A = wb0 + 64512;
    ushort_t* wbL3B = wb0 + 82944;           // ends 101,376 < 230,400 halfs ok

    norm_partial<<<dim3(18 * 8, 2), 256, 0, stream>>>(fq_feats, fs_feats, partial);
    norm_finalize<<<(2 * 18 * HW + 255) / 256, 256, 0, stream>>>(partial, invn);

    // weight prep (after norm_finalize frees `partial`)
    wprep<9, 10, false><<<54, 256, 0, stream>>>(w1, wbL1A);
    wprep<9, 10, true ><<<54, 256, 0, stream>>>(w1, wbL1B);
    wprep<10, 10, false><<<72, 256, 0, stream>>>(w2, wbL2A);
    wprep<10, 10, true ><<<72, 256, 0, stream>>>(w2, wbL2B);
    wprep<10, 1, false><<<72, 256, 0, stream>>>(w3, wbL3A);
    wprep<10, 1, true ><<<72, 256, 0, stream>>>(w3, wbL3B);

    // correlation GEMM in two l-batches of 9 (buffers reused)
    for (int half = 0; half < 2; ++half) {
        int base = half * 9;
        transpose_f16<<<dim3(16, 7, 18), 256, 0, stream>>>(fq_feats, fs_feats, At, Bt, base);
        corr_gemm_mfma<<<dim3(7, 7, 9), 256, 0, stream>>>(At, Bt, invn, corr, base);
    }

    // path A
    conv4d_v5<9, 10, false><<<dim3(400, NB), 256, 0, stream>>>(corr, wbL1A, buf1);
    conv4d_v5<10, 10, false><<<dim3(400, NB), 256, 0, stream>>>(buf1, wbL2A, buf2);
    conv4d_v5<10, 1, false><<<dim3(400, NB), 256, 0, stream>>>(buf2, wbL3A, c4);
    // path B (tap-swapped weights), accumulated into c4
    conv4d_v5<9, 10, false><<<dim3(400, NB), 256, 0, stream>>>(corr, wbL1B, buf1);
    conv4d_v5<10, 10, false><<<dim3(400, NB), 256, 0, stream>>>(buf1, wbL2B, buf2);
    conv4d_v5<10, 1, true ><<<dim3(400, NB), 256, 0, stream>>>(buf2, wbL3B, c4);

    softmax_av<<<dim3(400, NB), 256, 0, stream>>>(c4, f_s, att);
    final_fq<<<dim3(400, NB), 256, 0, stream>>>(f_q, att, out);

    (void)in_sizes; (void)n_in; (void)out_size; (void)ws_size;
}

// Round 8
// 421.854 us; speedup vs baseline: 3.5952x; 1.3322x over previous
//
#include <hip/hip_runtime.h>
#include <math.h>
#include <stddef.h>

#define L9   9
#define NB   2
#define CF   1024
#define HW   400     // 20*20
#define CH   256
#define TEMPF 20.0f
#define EPSF  1e-12f

typedef _Float16 half8 __attribute__((ext_vector_type(8)));
typedef float f32x4 __attribute__((ext_vector_type(4)));
typedef unsigned short ushort_t;

// ---------------------------------------------------------------------------
// Kernel 1 (v2): sums of squares over C, vectorized float4 along ij.
// grid (16 chunks, 18 lb, 2 t), block 256 (200 active: half=tid/100, p4=tid%100).
// partial2[t][lb][sub(32)][400], sub = chunk*2 + half (32 channels each).
// ---------------------------------------------------------------------------
__global__ __launch_bounds__(256) void norm_partial2(const float* __restrict__ fq,
                                                     const float* __restrict__ fs,
                                                     float* __restrict__ partial2) {
    int chunk = blockIdx.x, lb = blockIdx.y, t = blockIdx.z;
    int tid = threadIdx.x;
    if (tid >= 200) return;
    int half = tid / 100, p4 = tid - half * 100;
    const float* src = (t == 0 ? fq : fs) + (size_t)lb * CF * HW + p4 * 4;
    int c0 = chunk * 64 + half;
    f32x4 acc = {};
    #pragma unroll 8
    for (int it = 0; it < 32; ++it) {
        const float4 v = *(const float4*)(src + (size_t)(c0 + it * 2) * HW);
        acc[0] = fmaf(v.x, v.x, acc[0]);
        acc[1] = fmaf(v.y, v.y, acc[1]);
        acc[2] = fmaf(v.z, v.z, acc[2]);
        acc[3] = fmaf(v.w, v.w, acc[3]);
    }
    float* dst = partial2 + ((size_t)((t * 18 + lb) * 32) + chunk * 2 + half) * HW + p4 * 4;
    *(f32x4*)dst = acc;
}

// ---------------------------------------------------------------------------
// Kernel 2 (v2): finalize inverse norms (sum 32 subs).
// ---------------------------------------------------------------------------
__global__ __launch_bounds__(256) void norm_finalize2(const float* __restrict__ partial2,
                                                      float* __restrict__ invn) {
    int idx = blockIdx.x * 256 + threadIdx.x;
    if (idx >= 2 * 18 * HW) return;
    int t_lb = idx / HW;
    int ij = idx - t_lb * HW;
    const float* p = partial2 + (size_t)t_lb * 32 * HW + ij;
    float ss = 0.f;
    #pragma unroll
    for (int c = 0; c < 32; ++c) ss += p[c * HW];
    invn[idx] = 1.0f / fmaxf(sqrtf(ss), EPSF);
}

// ---------------------------------------------------------------------------
// Kernel 3a: transpose+convert: fq[lb][c][ij] -> At[li][ij][c] fp16 (ditto fs->Bt)
// ---------------------------------------------------------------------------
__global__ __launch_bounds__(256) void transpose_f16(const float* __restrict__ fq,
                                                     const float* __restrict__ fs,
                                                     ushort_t* __restrict__ At,
                                                     ushort_t* __restrict__ Bt,
                                                     int lb_base) {
    __shared__ float tile[64][65];
    int z = blockIdx.z;
    int tsel = z / 9, li = z - tsel * 9;
    int lb = lb_base + li;
    const float* src = (tsel ? fs : fq) + (size_t)lb * CF * HW;
    ushort_t* dst = (tsel ? Bt : At) + (size_t)li * HW * CF;
    int c0 = blockIdx.x * 64, ij0 = blockIdx.y * 64;
    int tid = threadIdx.x;
    int cl = tid >> 6;
    int col = tid & 63;
    #pragma unroll
    for (int rr = 0; rr < 16; ++rr) {
        int c_local = rr * 4 + cl;
        int ij = ij0 + col;
        tile[c_local][col] = (ij < HW) ? src[(size_t)(c0 + c_local) * HW + ij] : 0.f;
    }
    __syncthreads();
    int cp = (tid & 31) * 2;
    int rowsel = tid >> 5;
    #pragma unroll
    for (int rr = 0; rr < 8; ++rr) {
        int ij_local = rr * 8 + rowsel;
        int ij = ij0 + ij_local;
        if (ij < HW) {
            union { _Float16 h; ushort_t u; } h0, h1;
            h0.h = (_Float16)tile[cp][ij_local];
            h1.h = (_Float16)tile[cp + 1][ij_local];
            ushort2 o; o.x = h0.u; o.y = h1.u;
            *(ushort2*)(dst + (size_t)ij * CF + c0 + cp) = o;
        }
    }
}

// ---------------------------------------------------------------------------
// Kernel 3b: MFMA fp16 correlation GEMM -> f16 corr output (feeds convs only).
// ---------------------------------------------------------------------------
__global__ __launch_bounds__(256) void corr_gemm_mfma(const ushort_t* __restrict__ At,
                                                      const ushort_t* __restrict__ Bt,
                                                      const float* __restrict__ invn,
                                                      ushort_t* __restrict__ corr,
                                                      int lb_base) {
    __shared__ ushort_t As[64][72];
    __shared__ ushort_t Bs[64][72];
    int li = blockIdx.z, lb = lb_base + li;
    int l = lb >> 1, b = lb & 1;
    int i0 = blockIdx.y * 64, j0 = blockIdx.x * 64;
    int tid = threadIdx.x, lane = tid & 63, w = tid >> 6;
    int mw = (w >> 1) * 32, nw = (w & 1) * 32;
    f32x4 acc[2][2] = {};
    const ushort_t* Abase = At + (size_t)li * HW * CF;
    const ushort_t* Bbase = Bt + (size_t)li * HW * CF;

    for (int kt = 0; kt < 16; ++kt) {
        int c0 = kt * 64;
        __syncthreads();
        #pragma unroll
        for (int p = 0; p < 2; ++p) {
            int idx = tid + p * 256;
            int row = idx >> 3, c8 = idx & 7;
            uint4 va = make_uint4(0, 0, 0, 0), vb = make_uint4(0, 0, 0, 0);
            if (i0 + row < HW) va = *(const uint4*)(Abase + (size_t)(i0 + row) * CF + c0 + c8 * 8);
            if (j0 + row < HW) vb = *(const uint4*)(Bbase + (size_t)(j0 + row) * CF + c0 + c8 * 8);
            *(uint4*)&As[row][c8 * 8] = va;
            *(uint4*)&Bs[row][c8 * 8] = vb;
        }
        __syncthreads();
        #pragma unroll
        for (int ks = 0; ks < 2; ++ks) {
            int k0 = ks * 32 + (lane >> 4) * 8;
            half8 a0 = *(const half8*)&As[mw + (lane & 15)][k0];
            half8 a1 = *(const half8*)&As[mw + 16 + (lane & 15)][k0];
            half8 b0 = *(const half8*)&Bs[nw + (lane & 15)][k0];
            half8 b1 = *(const half8*)&Bs[nw + 16 + (lane & 15)][k0];
            acc[0][0] = __builtin_amdgcn_mfma_f32_16x16x32_f16(a0, b0, acc[0][0], 0, 0, 0);
            acc[0][1] = __builtin_amdgcn_mfma_f32_16x16x32_f16(a0, b1, acc[0][1], 0, 0, 0);
            acc[1][0] = __builtin_amdgcn_mfma_f32_16x16x32_f16(a1, b0, acc[1][0], 0, 0, 0);
            acc[1][1] = __builtin_amdgcn_mfma_f32_16x16x32_f16(a1, b1, acc[1][1], 0, 0, 0);
        }
    }
    int obase = (b * 9 + l) * HW;
    #pragma unroll
    for (int mi = 0; mi < 2; ++mi) {
        #pragma unroll
        for (int ni = 0; ni < 2; ++ni) {
            #pragma unroll
            for (int r = 0; r < 4; ++r) {
                int ij = i0 + mw + mi * 16 + (lane >> 4) * 4 + r;
                int km = j0 + nw + ni * 16 + (lane & 15);
                if (ij < HW && km < HW) {
                    union { _Float16 h; ushort_t u; } cv;
                    cv.h = (_Float16)(acc[mi][ni][r] * invn[lb * HW + ij] * invn[7200 + lb * HW + km]);
                    corr[(size_t)(obase + ij) * HW + km] = cv.u;
                }
            }
        }
    }
}

// ---------------------------------------------------------------------------
// Kernel W (v5): weight prep — B-fragment tables, fp16.
// wb[ch][dd][n(16)][k(32)]: k = ci_local*9 + pl(di,dj), zero-padded to 32.
// ---------------------------------------------------------------------------
template <int CIN, int COUT, bool SWAP>
__global__ __launch_bounds__(256) void wprep(const float* __restrict__ wt,
                                             ushort_t* __restrict__ wb) {
    const int NCH = (CIN + 2) / 3;
    int idx = blockIdx.x * 256 + threadIdx.x;
    int total = NCH * 4608;
    if (idx >= total) return;
    int k = idx & 31, n = (idx >> 5) & 15, dd = (idx >> 9) % 9, ch = idx / 4608;
    int nc = CIN - ch * 3; if (nc > 3) nc = 3;
    float v = 0.f;
    if (n < COUT && k < nc * 9) {
        int cil = k / 9, pl = k - cil * 9, ci = ch * 3 + cil;
        int di = pl / 3, dj = pl % 3, dk = dd / 3, dm = dd % 3;
        int widx = SWAP ? ((((n * CIN + ci) * 3 + dk) * 3 + dm) * 3 + di) * 3 + dj
                        : ((((n * CIN + ci) * 3 + di) * 3 + dj) * 3 + dk) * 3 + dm;
        v = wt[widx];
    }
    union { _Float16 h; ushort_t u; } cv; cv.h = (_Float16)v;
    wb[idx] = cv.u;
}

// ---------------------------------------------------------------------------
// Kernel 4 (v6): 4D conv + ReLU via MFMA implicit GEMM, f16 in / f16-or-f32 out.
// Same structure as v5 (verified), but input is f16 -> staging is a raw
// ushort copy (no cvt, half the global bytes).
// ---------------------------------------------------------------------------
template <int CIN, int COUT, bool OUTF16, bool ACCUM>
__global__ __launch_bounds__(256) void conv4d_v6(const ushort_t* __restrict__ in,
                                                 const ushort_t* __restrict__ wb,
                                                 void* __restrict__ outv) {
    constexpr int NCH = (CIN + 2) / 3;
    __shared__ __align__(16) ushort_t Ah[484 * 40];   // 38,720 B
    const int b = blockIdx.y, ij = blockIdx.x;
    const int i = ij / 20, j = ij - (ij / 20) * 20;
    const int tid = threadIdx.x, wv = tid >> 6, lane = tid & 63;
    const int m16 = lane & 15, q = lane >> 4;

    for (int p = tid; p < 484 * 20; p += 256) ((uint*)Ah)[p] = 0;

    int baseh[7];
    #pragma unroll
    for (int s = 0; s < 7; ++s) {
        int t = wv + 4 * s;
        if (t < 25) {
            int km = t * 16 + m16;
            int kk = km / 20, mm = km - kk * 20;
            baseh[s] = (kk * 22 + mm) * 40 + q * 8;
        } else baseh[s] = 0;
    }
    f32x4 acc[7] = {};

    const ushort_t* in_b = in + (size_t)b * CIN * HW * HW;
    const ushort_t* wfr = wb + m16 * 32 + q * 8;

    const int km1 = tid;
    const int km2 = tid + 256;
    const bool r2ok = tid < 144;
    const int r1 = (km1 / 20 + 1) * 22 + (km1 % 20) + 1;
    const int r2 = (km2 / 20 + 1) * 22 + (km2 % 20) + 1;

    __syncthreads();   // zeroing complete

    #pragma unroll
    for (int ch = 0; ch < NCH; ++ch) {
        const int nc = (CIN - ch * 3 > 3) ? 3 : (CIN - ch * 3);
        if (ch > 0) __syncthreads();
        // ---- stage chunk: rows own km, pack 4 k-slots per b64 write ----
        #pragma unroll
        for (int g4 = 0; g4 < 7; ++g4) {
            if (g4 * 4 < nc * 9) {
                ushort_t h1[4], h2[4];
                #pragma unroll
                for (int u = 0; u < 4; ++u) {
                    const int slot = g4 * 4 + u;
                    ushort_t v1 = 0, v2 = 0;
                    if (slot < nc * 9) {
                        const int cil = slot / 9, pl = slot - cil * 9;
                        const int di = pl / 3, dj = pl - di * 3;
                        const int ii = i + di - 1, jj = j + dj - 1;
                        if ((unsigned)ii < 20u && (unsigned)jj < 20u) {
                            const ushort_t* src = in_b + ((size_t)(ch * 3 + cil) * HW + ii * 20 + jj) * HW;
                            v1 = src[km1];
                            if (r2ok) v2 = src[km2];
                        }
                    }
                    h1[u] = v1; h2[u] = v2;
                }
                union { ushort_t us[4]; uint2 u2; } p1, p2;
                p1.us[0] = h1[0]; p1.us[1] = h1[1]; p1.us[2] = h1[2]; p1.us[3] = h1[3];
                p2.us[0] = h2[0]; p2.us[1] = h2[1]; p2.us[2] = h2[2]; p2.us[3] = h2[3];
                *(uint2*)&Ah[r1 * 40 + g4 * 4] = p1.u2;
                if (r2ok) *(uint2*)&Ah[r2 * 40 + g4 * 4] = p2.u2;
            }
        }
        __syncthreads();
        // ---- MFMA phase ----
        const ushort_t* wch = wfr + ch * 4608;
        #pragma unroll
        for (int dd = 0; dd < 9; ++dd) {
            half8 bf = *(const half8*)(wch + dd * 512);
            const int doff = ((dd / 3) * 22 + (dd % 3)) * 40;
            #pragma unroll
            for (int s = 0; s < 7; ++s) {
                if (wv + 4 * s < 25) {
                    half8 af = *(const half8*)(Ah + baseh[s] + doff);
                    acc[s] = __builtin_amdgcn_mfma_f32_16x16x32_f16(af, bf, acc[s], 0, 0, 0);
                }
            }
        }
    }

    // epilogue: col=lane&15 -> co, row=q*4+r -> km
    const int co = m16;
    if (co < COUT) {
        #pragma unroll
        for (int s = 0; s < 7; ++s) {
            int t = wv + 4 * s;
            if (t < 25) {
                int km0 = t * 16 + q * 4;
                size_t o = ((size_t)(b * COUT + co) * HW + ij) * HW + km0;
                if (OUTF16) {
                    ushort_t* op = (ushort_t*)outv + o;
                    union { ushort_t us[4]; uint2 u2; } pk;
                    #pragma unroll
                    for (int r = 0; r < 4; ++r) {
                        union { _Float16 h; ushort_t u16; } cv;
                        cv.h = (_Float16)fmaxf(acc[s][r], 0.f);
                        pk.us[r] = cv.u16;
                    }
                    *(uint2*)op = pk.u2;
                } else {
                    float* op = (float*)outv + o;
                    #pragma unroll
                    for (int r = 0; r < 4; ++r) {
                        float v = fmaxf(acc[s][r], 0.f);
                        if (ACCUM) op[r] += v; else op[r] = v;
                    }
                }
            }
        }
    }
}

// ---------------------------------------------------------------------------
// Kernel 5: softmax over s + att_fq = attn . V
// ---------------------------------------------------------------------------
__global__ __launch_bounds__(256) void softmax_av(const float* __restrict__ c4,
                                                  const float* __restrict__ f_s,
                                                  float* __restrict__ att_out) {
    __shared__ float p[HW];
    __shared__ float red[256];
    int b = blockIdx.y, q = blockIdx.x;
    int tid = threadIdx.x;
    const float* row = c4 + ((size_t)b * HW + q) * HW;
    float v0 = row[tid] * TEMPF;
    float v1 = (tid < HW - 256) ? row[tid + 256] * TEMPF : -1e30f;
    red[tid] = fmaxf(v0, v1);
    __syncthreads();
    for (int s = 128; s > 0; s >>= 1) {
        if (tid < s) red[tid] = fmaxf(red[tid], red[tid + s]);
        __syncthreads();
    }
    float mx = red[0];
    __syncthreads();
    float e0 = expf(v0 - mx);
    float e1 = (tid < HW - 256) ? expf(v1 - mx) : 0.f;
    p[tid] = e0;
    if (tid < HW - 256) p[tid + 256] = e1;
    red[tid] = e0 + e1;
    __syncthreads();
    for (int s = 128; s > 0; s >>= 1) {
        if (tid < s) red[tid] += red[tid + s];
        __syncthreads();
    }
    float inv = 1.0f / red[0];
    const float* vrow = f_s + (size_t)(b * CH + tid) * HW;
    float acc = 0.f;
    for (int s = 0; s < HW; ++s) acc = fmaf(p[s], vrow[s], acc);
    att_out[(size_t)(b * CH + tid) * HW + q] = acc * inv;
}

// ---------------------------------------------------------------------------
// Kernel 6: fq = l2norm(f_q, ch) + 0.5 * l2norm(att_fq, ch)
// ---------------------------------------------------------------------------
__global__ __launch_bounds__(256) void final_fq(const float* __restrict__ f_q,
                                                const float* __restrict__ att,
                                                float* __restrict__ out_fq) {
    __shared__ float red[256];
    int b = blockIdx.y, q = blockIdx.x;
    int tid = threadIdx.x;
    size_t idx = (size_t)(b * CH + tid) * HW + q;
    float f = f_q[idx];
    float a = att[idx];
    red[tid] = f * f;
    __syncthreads();
    for (int s = 128; s > 0; s >>= 1) {
        if (tid < s) red[tid] += red[tid + s];
        __syncthreads();
    }
    float invf = 1.0f / fmaxf(sqrtf(red[0]), EPSF);
    __syncthreads();
    red[tid] = a * a;
    __syncthreads();
    for (int s = 128; s > 0; s >>= 1) {
        if (tid < s) red[tid] += red[tid + s];
        __syncthreads();
    }
    float inva = 1.0f / fmaxf(sqrtf(red[0]), EPSF);
    out_fq[idx] = f * invf + 0.5f * a * inva;
}

// ---------------------------------------------------------------------------
extern "C" void kernel_launch(void* const* d_in, const int* in_sizes, int n_in,
                              void* d_out, int out_size, void* d_ws, size_t ws_size,
                              hipStream_t stream) {
    const float* fq_feats = (const float*)d_in[0];
    const float* fs_feats = (const float*)d_in[1];
    const float* f_q      = (const float*)d_in[2];
    const float* f_s      = (const float*)d_in[3];
    const float* w1       = (const float*)d_in[4];
    const float* w2       = (const float*)d_in[5];
    const float* w3       = (const float*)d_in[6];
    float* out = (float*)d_out;              // fq at 0, att_fq at 204800

    float* ws      = (float*)d_ws;
    float* wbuf    = ws;                     // 115,200 fl: weight tables
    float* invn    = wbuf + 115200;          // 14,400
    float* corr    = invn + 14400;           // 2,880,000 fl region (f16 corr uses half)
    float* buf1    = corr + 2880000;         // 3,200,000 (partial2 first, then At / conv f16)
    float* buf2    = buf1 + 3200000;         // 3,200,000 (Bt / conv f16)
    float* c4      = buf2 + 3200000;         // 320,000
    float* att     = out + 204800;

    float* partial2 = buf1;                  // 460,800 floats, dead after finalize
    ushort_t* corr_h = (ushort_t*)corr;
    ushort_t* At = (ushort_t*)buf1;
    ushort_t* Bt = (ushort_t*)buf2;
    ushort_t* b1h = (ushort_t*)buf1;
    ushort_t* b2h = (ushort_t*)buf2;

    // weight tables overlay wbuf: L1 = 13,824 halfs; L2/L3 = 18,432
    ushort_t* wb0   = (ushort_t*)wbuf;
    ushort_t* wbL1A = wb0;
    ushort_t* wbL1B = wb0 + 13824;
    ushort_t* wbL2A = wb0 + 27648;
    ushort_t* wbL2B = wb0 + 46080;
    ushort_t* wbL3A = wb0 + 64512;
    ushort_t* wbL3B = wb0 + 82944;           // ends 101,376 < 230,400 halfs ok

    norm_partial2<<<dim3(16, 18, 2), 256, 0, stream>>>(fq_feats, fs_feats, partial2);
    norm_finalize2<<<(2 * 18 * HW + 255) / 256, 256, 0, stream>>>(partial2, invn);

    wprep<9, 10, false><<<54, 256, 0, stream>>>(w1, wbL1A);
    wprep<9, 10, true ><<<54, 256, 0, stream>>>(w1, wbL1B);
    wprep<10, 10, false><<<72, 256, 0, stream>>>(w2, wbL2A);
    wprep<10, 10, true ><<<72, 256, 0, stream>>>(w2, wbL2B);
    wprep<10, 1, false><<<72, 256, 0, stream>>>(w3, wbL3A);
    wprep<10, 1, true ><<<72, 256, 0, stream>>>(w3, wbL3B);

    // correlation GEMM in two l-batches of 9 (buffers reused)
    for (int half = 0; half < 2; ++half) {
        int base = half * 9;
        transpose_f16<<<dim3(16, 7, 18), 256, 0, stream>>>(fq_feats, fs_feats, At, Bt, base);
        corr_gemm_mfma<<<dim3(7, 7, 9), 256, 0, stream>>>(At, Bt, invn, corr_h, base);
    }

    // path A
    conv4d_v6<9, 10, true, false><<<dim3(400, NB), 256, 0, stream>>>(corr_h, wbL1A, b1h);
    conv4d_v6<10, 10, true, false><<<dim3(400, NB), 256, 0, stream>>>(b1h, wbL2A, b2h);
    conv4d_v6<10, 1, false, false><<<dim3(400, NB), 256, 0, stream>>>(b2h, wbL3A, c4);
    // path B (tap-swapped weights), accumulated into c4
    conv4d_v6<9, 10, true, false><<<dim3(400, NB), 256, 0, stream>>>(corr_h, wbL1B, b1h);
    conv4d_v6<10, 10, true, false><<<dim3(400, NB), 256, 0, stream>>>(b1h, wbL2B, b2h);
    conv4d_v6<10, 1, false, true ><<<dim3(400, NB), 256, 0, stream>>>(b2h, wbL3B, c4);

    softmax_av<<<dim3(400, NB), 256, 0, stream>>>(c4, f_s, att);
    final_fq<<<dim3(400, NB), 256, 0, stream>>>(f_q, att, out);

    (void)in_sizes; (void)n_in; (void)out_size; (void)ws_size;
}